// Round 5
// baseline (217.083 us; speedup 1.0000x reference)
//
#include <hip/hip_runtime.h>
#include <hip/hip_bf16.h>

typedef unsigned short u16;
typedef __bf16 bfx8 __attribute__((ext_vector_type(8)));
typedef float fx4 __attribute__((ext_vector_type(4)));

#define SEQ 2048
#define DIM 1024
#define NBATCH 4
#define SCALE 0.03125f  // 1/sqrt(1024)
#define NEL ((size_t)NBATCH * SEQ * DIM)   // 8388608 elems per Q/K/V

__device__ inline u16 f2bf(float f) {
    __bf16 h = (__bf16)f;
    return __builtin_bit_cast(unsigned short, h);
}

// async global->LDS, 16B per lane (dst must be wave-uniform base + lane*16;
// padding the LDS row stride is NOT possible -> xor-swizzle the SOURCE chunk)
#define GLL(gp, lp) __builtin_amdgcn_global_load_lds( \
    (const __attribute__((address_space(1))) unsigned int*)(gp), \
    (__attribute__((address_space(3))) unsigned int*)(lp), 16, 0, 0)

// ---------------------------------------------------------------------------
// prep: blocks [0,8192): convert x -> XB (bf16)
//       blocks [8192,10240): straight-convert Wq,Wk -> WBq,WBk
//       blocks [10240,11264): transpose Wv -> WTv[e][d]
//       blocks [11264,11296): zero Lrow
// ---------------------------------------------------------------------------
__global__ __launch_bounds__(256) void prep(
    const float* __restrict__ X,
    const float* __restrict__ Wq, const float* __restrict__ Wk,
    const float* __restrict__ Wv,
    u16* __restrict__ XB, u16* __restrict__ WB, u16* __restrict__ WTv,
    float* __restrict__ Lrow)
{
    __shared__ u16 t[32][33];
    int bid = blockIdx.x;
    int tid = threadIdx.x;
    if (bid < 8192) {
        size_t i = (size_t)bid * 256 + tid;
        float4 v = ((const float4*)X)[i];
        uint2 pk;
        pk.x = (unsigned)f2bf(v.x) | ((unsigned)f2bf(v.y) << 16);
        pk.y = (unsigned)f2bf(v.z) | ((unsigned)f2bf(v.w) << 16);
        ((uint2*)XB)[i] = pk;
    } else if (bid < 10240) {
        int b2 = bid - 8192;                       // 0..2047
        const float* W = (b2 < 1024) ? Wq : Wk;
        u16* out = WB + (size_t)(b2 >> 10) * 1024 * 1024;
        size_t i = (size_t)(b2 & 1023) * 256 + tid;  // float4 units
        float4 v = ((const float4*)W)[i];
        uint2 pk;
        pk.x = (unsigned)f2bf(v.x) | ((unsigned)f2bf(v.y) << 16);
        pk.y = (unsigned)f2bf(v.z) | ((unsigned)f2bf(v.w) << 16);
        ((uint2*)out)[i] = pk;
    } else if (bid < 11264) {
        int t2 = bid - 10240;                      // 0..1023 tiles
        int n0 = (t2 & 31) * 32, k0 = (t2 >> 5) * 32;
        int tx = tid & 31, ty = tid >> 5;
        #pragma unroll
        for (int i = 0; i < 32; i += 8)
            t[ty + i][tx] = f2bf(Wv[(size_t)(k0 + ty + i) * 1024 + n0 + tx]);
        __syncthreads();
        #pragma unroll
        for (int i = 0; i < 32; i += 8)
            WTv[(size_t)(n0 + ty + i) * 1024 + k0 + tx] = t[tx][ty + i];
    } else {
        int i = (bid - 11264) * 256 + tid;   // 8192 floats
        Lrow[i] = 0.0f;
    }
}

// ---------------------------------------------------------------------------
// gemm_m: MT[d2][d1] = sum_e WBk[d2][e] * WBq[d1][e].  Grid (8,8), small.
// ---------------------------------------------------------------------------
__global__ __launch_bounds__(256) void gemm_m(
    const u16* __restrict__ WBk, const u16* __restrict__ WBq, u16* __restrict__ MT)
{
    int m0 = blockIdx.y * 128, n0 = blockIdx.x * 128;
    __shared__ __align__(16) u16 As[128 * 32];
    __shared__ __align__(16) u16 Bs[128 * 32];
    int tid = threadIdx.x, lane = tid & 63, w = tid >> 6;
    int wm = w >> 1, wn = w & 1, lo = lane & 15, qd = lane >> 4;
    fx4 acc[4][4] = {};

    int c0 = tid, c1 = tid + 256;
    const u16* a0 = WBk + (size_t)(m0 + (c0 >> 2)) * 1024 + (((c0 & 3) ^ ((c0 >> 2) & 3)) * 8);
    const u16* a1 = WBk + (size_t)(m0 + (c1 >> 2)) * 1024 + (((c1 & 3) ^ ((c1 >> 2) & 3)) * 8);
    const u16* b0 = WBq + (size_t)(n0 + (c0 >> 2)) * 1024 + (((c0 & 3) ^ ((c0 >> 2) & 3)) * 8);
    const u16* b1 = WBq + (size_t)(n0 + (c1 >> 2)) * 1024 + (((c1 & 3) ^ ((c1 >> 2) & 3)) * 8);

    int sw = (qd ^ (lo & 3)) * 8;
    for (int k0 = 0; k0 < 1024; k0 += 32) {
        GLL(a0 + k0, &As[(size_t)c0 * 8]);
        GLL(a1 + k0, &As[(size_t)c1 * 8]);
        GLL(b0 + k0, &Bs[(size_t)c0 * 8]);
        GLL(b1 + k0, &Bs[(size_t)c1 * 8]);
        __syncthreads();
        bfx8 af[4], bf[4];
        #pragma unroll
        for (int i = 0; i < 4; i++)
            af[i] = *(const bfx8*)(&As[(wm * 64 + i * 16 + lo) * 32 + sw]);
        #pragma unroll
        for (int j = 0; j < 4; j++)
            bf[j] = *(const bfx8*)(&Bs[(wn * 64 + j * 16 + lo) * 32 + sw]);
        #pragma unroll
        for (int i = 0; i < 4; i++)
            #pragma unroll
            for (int j = 0; j < 4; j++)
                acc[i][j] = __builtin_amdgcn_mfma_f32_16x16x32_bf16(af[i], bf[j], acc[i][j], 0, 0, 0);
        __syncthreads();
    }
    #pragma unroll
    for (int i = 0; i < 4; i++)
        #pragma unroll
        for (int j = 0; j < 4; j++)
            #pragma unroll
            for (int r = 0; r < 4; r++)
                MT[(size_t)(m0 + wm * 64 + i * 16 + qd * 4 + r) * 1024
                   + n0 + wn * 64 + j * 16 + lo] = f2bf(acc[i][j][r]);
}

// ---------------------------------------------------------------------------
// gemm256: z=0: Y = XB x MT^T; z=1: V = XB x WTv^T stored TRANSPOSED.
// r5: 1024 thr / 16 waves (4m x 4n), per-wave 64x64 (acc[4][4] = 64 AGPR ->
// total regs ~120/wave -> 4 waves/SIMD instead of r4's 2).  256x256 tile,
// BK=64, dbuf 128 KiB, 2 phases/K-tile (16 MFMA each), counted vmcnt(4),
// XCD-chunked grid mapping (r4, FETCH 103->24.7 MB verified).
// r4 post-mortem: 8-wave version was LDS-port + phase-serialization bound
// at 2 waves/SIMD (VGPR 116 + 128 AGPR acc ~ 244 regs).
// ---------------------------------------------------------------------------
__global__ __launch_bounds__(1024, 4) void gemm256(
    const u16* __restrict__ XB, const u16* __restrict__ MT,
    const u16* __restrict__ WTv,
    u16* __restrict__ Yo, u16* __restrict__ VTo)
{
    const int work = ((blockIdx.x & 7) << 5) + ((int)blockIdx.x >> 3);
    const int z = work >> 7;                 // 0..1
    const int m0 = ((work >> 2) & 31) * 256; // 32 m-blocks
    const int n0 = (work & 3) * 256;         // 4 n-blocks
    const u16* Bop = (z == 0) ? MT : WTv;

    // [0,16384): A buf0   [16384,32768): A buf1
    // [32768,49152): B buf0   [49152,65536): B buf1      (u16 elements)
    __shared__ __align__(16) u16 SM[65536];   // 128 KiB

    const int tid = threadIdx.x, lane = tid & 63, w = tid >> 6;
    const int wm = w >> 2, wn = w & 3, lo = lane & 15, qd = lane >> 4;
    const int swl = lo & 7;

    fx4 acc[4][4] = {};

    // staging: per K-tile 2048 chunks (16B) per operand, 2 per thread.
    const u16* sA[2]; const u16* sB[2]; int dofs[2];
    #pragma unroll
    for (int p = 0; p < 2; ++p) {
        int n = p * 1024 + tid;
        int row = n >> 3;
        int c = (n & 7) ^ (row & 7);
        sA[p] = XB  + (size_t)(m0 + row) * 1024 + c * 8;
        sB[p] = Bop + (size_t)(n0 + row) * 1024 + c * 8;
        dofs[p] = n * 8;                      // u16 elements (16B per chunk)
    }

    auto stage = [&](int kt2) {
        const int bb = (kt2 & 1) * 16384;
        #pragma unroll
        for (int p = 0; p < 2; ++p) GLL(sA[p] + kt2 * 64, &SM[bb + dofs[p]]);
        #pragma unroll
        for (int p = 0; p < 2; ++p) GLL(sB[p] + kt2 * 64, &SM[32768 + bb + dofs[p]]);
    };

    stage(0);
    stage(1);
    asm volatile("s_waitcnt vmcnt(4)" ::: "memory");
    __builtin_amdgcn_s_barrier();
    asm volatile("" ::: "memory");

    for (int kt = 0; kt < 16; ++kt) {
        const u16* Ab = SM + (kt & 1) * 16384;
        const u16* Bb = SM + 32768 + (kt & 1) * 16384;

        #pragma unroll
        for (int ks = 0; ks < 2; ++ks) {
            bfx8 af[4], bf[4];
            const int sw = ((ks * 4 + qd) ^ swl) * 8;
            #pragma unroll
            for (int i = 0; i < 4; ++i)
                af[i] = *(const bfx8*)(Ab + (wm * 64 + i * 16 + lo) * 64 + sw);
            #pragma unroll
            for (int j = 0; j < 4; ++j)
                bf[j] = *(const bfx8*)(Bb + (wn * 64 + j * 16 + lo) * 64 + sw);
            __builtin_amdgcn_s_barrier();
            asm volatile("s_waitcnt lgkmcnt(0)" ::: "memory");
            __builtin_amdgcn_sched_barrier(0);
            __builtin_amdgcn_s_setprio(1);
            #pragma unroll
            for (int i = 0; i < 4; ++i)
                #pragma unroll
                for (int j = 0; j < 4; ++j)
                    acc[i][j] = __builtin_amdgcn_mfma_f32_16x16x32_bf16(
                        af[i], bf[j], acc[i][j], 0, 0, 0);
            __builtin_amdgcn_s_setprio(0);
            __builtin_amdgcn_s_barrier();
            asm volatile("" ::: "memory");
        }
        if (kt < 14) stage(kt + 2);
        if (kt < 15) {
            if (kt < 14) asm volatile("s_waitcnt vmcnt(4)" ::: "memory");
            else         asm volatile("s_waitcnt vmcnt(0)" ::: "memory");
            __builtin_amdgcn_s_barrier();
            asm volatile("" ::: "memory");
        }
    }

    if (z == 0) {
        #pragma unroll
        for (int i = 0; i < 4; i++)
            #pragma unroll
            for (int j = 0; j < 4; j++)
                #pragma unroll
                for (int r = 0; r < 4; r++) {
                    int row = m0 + wm * 64 + i * 16 + qd * 4 + r;
                    int col = n0 + wn * 64 + j * 16 + lo;
                    Yo[(size_t)row * 1024 + col] = f2bf(acc[i][j][r]);
                }
    } else {
        // transpose epilogue via freed LDS: Ct[128][258] (66 KB, fits in SM).
        // half h covers global s-rows [m0 + h*128, +128) = waves wm in {2h,2h+1}.
        u16 (*Ct)[258] = (u16(*)[258])SM;
        const int bb = m0 >> 11;          // batch (tiles never straddle)
        const int sbase = m0 & 2047;
        #pragma unroll
        for (int h = 0; h < 2; ++h) {
            __syncthreads();
            if ((wm >> 1) == h) {
                #pragma unroll
                for (int i = 0; i < 4; i++)
                    #pragma unroll
                    for (int j = 0; j < 4; j++)
                        #pragma unroll
                        for (int r = 0; r < 4; r++)
                            Ct[(wm & 1) * 64 + i * 16 + qd * 4 + r]
                              [wn * 64 + j * 16 + lo] = f2bf(acc[i][j][r]);
            }
            __syncthreads();
            for (int e = tid; e < 16384; e += 1024) {
                int d = e >> 6, s2 = (e & 63) * 2;
                unsigned pk = (unsigned)Ct[s2][d] | ((unsigned)Ct[s2 + 1][d] << 16);
                *(unsigned*)&VTo[((size_t)bb * DIM + (n0 + d)) * SEQ
                                 + sbase + h * 128 + s2] = pk;
            }
        }
    }
}

// ---------------------------------------------------------------------------
// sgemm_exp: P = exp(scale*(Y x XB^T) masked), causal 128x128 tiles, bf16,
// UNNORMALIZED (clamped +-30).  Row sums -> atomicAdd.
// r4: XCD-chunked mapping (verified: FETCH dedup'd), 64 KiB dbuf pipeline.
// ---------------------------------------------------------------------------
__global__ __launch_bounds__(512) void sgemm_exp(
    const u16* __restrict__ Y, const u16* __restrict__ XB,
    u16* __restrict__ P, float* __restrict__ Lrow)
{
    const int k = blockIdx.x;                       // 0..543 (= 8 * 68)
    const int work = (k & 7) * 68 + (k >> 3);       // XCD-contiguous
    const int b = work / 136;
    const int t = work % 136;                       // triangular tile
    int i = (int)((sqrtf(8.0f * t + 1.0f) - 1.0f) * 0.5f);
    while ((i + 1) * (i + 2) / 2 <= t) i++;
    while (i * (i + 1) / 2 > t) i--;
    int j = t - i * (i + 1) / 2;

    const u16* Yb = Y + (size_t)b * SEQ * DIM;
    const u16* Xb = XB + (size_t)b * SEQ * DIM;
    u16* Pb = P + (size_t)b * SEQ * SEQ;
    float* Lb = Lrow + (size_t)b * SEQ;

    int m0 = i * 128, n0 = j * 128;

    // A0 [0,8192) A1 [8192,16384) B0 [16384,24576) B1 [24576,32768)  (u16)
    __shared__ __align__(16) u16 SM[32768];   // 64 KiB

    int tid = threadIdx.x, lane = tid & 63, w = tid >> 6;
    int wm = w >> 2, wn = w & 3, lo = lane & 15, qd = lane >> 4;
    int swl = lo & 7;

    fx4 acc[4][2] = {};

    int c0 = tid, c1 = tid + 512;        // 1024 chunks of 16B per operand
    const u16* a0 = Yb + (size_t)(m0 + (c0 >> 3)) * 1024 + (((c0 & 7) ^ ((c0 >> 3) & 7)) * 8);
    const u16* a1 = Yb + (size_t)(m0 + (c1 >> 3)) * 1024 + (((c1 & 7) ^ ((c1 >> 3) & 7)) * 8);
    const u16* b0 = Xb + (size_t)(n0 + (c0 >> 3)) * 1024 + (((c0 & 7) ^ ((c0 >> 3) & 7)) * 8);
    const u16* b1 = Xb + (size_t)(n0 + (c1 >> 3)) * 1024 + (((c1 & 7) ^ ((c1 >> 3) & 7)) * 8);
    int d0 = c0 * 8, d1 = c1 * 8;

    auto stage = [&](int kt2) {
        int bb = (kt2 & 1) * 8192;
        GLL(a0 + kt2 * 64, &SM[bb + d0]);
        GLL(a1 + kt2 * 64, &SM[bb + d1]);
        GLL(b0 + kt2 * 64, &SM[16384 + bb + d0]);
        GLL(b1 + kt2 * 64, &SM[16384 + bb + d1]);
    };

    stage(0);
    stage(1);
    asm volatile("s_waitcnt vmcnt(4)" ::: "memory");
    __builtin_amdgcn_s_barrier();
    asm volatile("" ::: "memory");

    for (int kt = 0; kt < 16; ++kt) {
        const u16* Ab = SM + (kt & 1) * 8192;
        const u16* Bb = SM + 16384 + (kt & 1) * 8192;

        #pragma unroll
        for (int kc = 0; kc < 2; ++kc) {
            bfx8 af[4], bf[2];
            int sw = ((kc * 4 + qd) ^ swl) * 8;
            #pragma unroll
            for (int ii = 0; ii < 4; ++ii)
                af[ii] = *(const bfx8*)(Ab + (wm * 64 + ii * 16 + lo) * 64 + sw);
            #pragma unroll
            for (int jn = 0; jn < 2; ++jn)
                bf[jn] = *(const bfx8*)(Bb + (wn * 32 + jn * 16 + lo) * 64 + sw);
            __builtin_amdgcn_s_barrier();
            asm volatile("s_waitcnt lgkmcnt(0)" ::: "memory");
            __builtin_amdgcn_sched_barrier(0);
            __builtin_amdgcn_s_setprio(1);
            #pragma unroll
            for (int ii = 0; ii < 4; ++ii)
                #pragma unroll
                for (int jn = 0; jn < 2; ++jn)
                    acc[ii][jn] = __builtin_amdgcn_mfma_f32_16x16x32_bf16(af[ii], bf[jn], acc[ii][jn], 0, 0, 0);
            __builtin_amdgcn_s_setprio(0);
            __builtin_amdgcn_s_barrier();
            asm volatile("" ::: "memory");
        }
        if (kt < 14) stage(kt + 2);
        if (kt < 15) {
            if (kt < 14) asm volatile("s_waitcnt vmcnt(4)" ::: "memory");
            else         asm volatile("s_waitcnt vmcnt(0)" ::: "memory");
            __builtin_amdgcn_s_barrier();
            asm volatile("" ::: "memory");
        }
    }

    #pragma unroll
    for (int ii = 0; ii < 4; ii++)
        #pragma unroll
        for (int r = 0; r < 4; r++) {
            int row = m0 + wm * 64 + ii * 16 + qd * 4 + r;
            float rs = 0.0f;
            #pragma unroll
            for (int jn = 0; jn < 2; jn++) {
                int col = n0 + wn * 32 + jn * 16 + lo;
                float s = acc[ii][jn][r] * SCALE;
                s = fminf(fmaxf(s, -30.0f), 30.0f);
                float p = (col > row) ? 0.0f : __expf(s);
                Pb[(size_t)row * SEQ + col] = f2bf(p);
                rs += p;
            }
            #pragma unroll
            for (int off = 1; off < 16; off <<= 1) rs += __shfl_xor(rs, off);
            if (lo == 0) atomicAdd(&Lb[row], rs);
        }
}

// ---------------------------------------------------------------------------
// pvgemm: O[q][d] = P[q][k] x VT[d][k] / L[q].  128x128 tiles, variable
// nkt = 2(qb+1).  r4: XCD-chunked + work-balanced qb-sets (verified).
// ---------------------------------------------------------------------------
__global__ __launch_bounds__(512) void pvgemm(
    const u16* __restrict__ P, const u16* __restrict__ VT,
    const float* __restrict__ Lrow, float* __restrict__ O)
{
    const int k = blockIdx.x;                 // 0..511 (= 8 * 64)
    const int xcd = k & 7, slot = k >> 3;     // slot 0..63
    const int b = xcd >> 1, half = xcd & 1;
    const int qsel = slot >> 3, db = slot & 7;
    const int qb = half ? (11 - qsel)
                        : ((qsel < 4) ? (15 - qsel) : (7 - qsel));
    int m0 = qb * 128, n0 = db * 128;
    int nkt = (qb + 1) * 2;                   // K-tiles of 64, >= 2

    const u16* Pb = P + (size_t)b * SEQ * SEQ;
    const u16* Vb = VT + (size_t)b * DIM * SEQ;
    const float* Lb = Lrow + (size_t)b * SEQ;
    float* Ob = O + (size_t)b * SEQ * DIM;

    // A0 [0,8192) A1 [8192,16384) B0 [16384,24576) B1 [24576,32768)  (u16)
    __shared__ __align__(16) u16 SM[32768];   // 64 KiB

    int tid = threadIdx.x, lane = tid & 63, w = tid >> 6;
    int wm = w >> 2, wn = w & 3, lo = lane & 15, qd = lane >> 4;
    int swl = lo & 7;

    fx4 acc[4][2] = {};

    int c0 = tid, c1 = tid + 512;
    const u16* a0 = Pb + (size_t)(m0 + (c0 >> 3)) * SEQ + (((c0 & 7) ^ ((c0 >> 3) & 7)) * 8);
    const u16* a1 = Pb + (size_t)(m0 + (c1 >> 3)) * SEQ + (((c1 & 7) ^ ((c1 >> 3) & 7)) * 8);
    const u16* b0 = Vb + (size_t)(n0 + (c0 >> 3)) * SEQ + (((c0 & 7) ^ ((c0 >> 3) & 7)) * 8);
    const u16* b1 = Vb + (size_t)(n0 + (c1 >> 3)) * SEQ + (((c1 & 7) ^ ((c1 >> 3) & 7)) * 8);
    int d0 = c0 * 8, d1 = c1 * 8;

    auto stage = [&](int kt2) {
        int bb = (kt2 & 1) * 8192;
        GLL(a0 + kt2 * 64, &SM[bb + d0]);
        GLL(a1 + kt2 * 64, &SM[bb + d1]);
        GLL(b0 + kt2 * 64, &SM[16384 + bb + d0]);
        GLL(b1 + kt2 * 64, &SM[16384 + bb + d1]);
    };

    stage(0);
    stage(1);                                // nkt >= 2 always
    asm volatile("s_waitcnt vmcnt(4)" ::: "memory");
    __builtin_amdgcn_s_barrier();
    asm volatile("" ::: "memory");

    for (int kt = 0; kt < nkt; ++kt) {
        const u16* Ab = SM + (kt & 1) * 8192;
        const u16* Bb = SM + 16384 + (kt & 1) * 8192;

        #pragma unroll
        for (int kc = 0; kc < 2; ++kc) {
            bfx8 af[4], bf[2];
            int sw = ((kc * 4 + qd) ^ swl) * 8;
            #pragma unroll
            for (int ii = 0; ii < 4; ++ii)
                af[ii] = *(const bfx8*)(Ab + (wm * 64 + ii * 16 + lo) * 64 + sw);
            #pragma unroll
            for (int jn = 0; jn < 2; ++jn)
                bf[jn] = *(const bfx8*)(Bb + (wn * 32 + jn * 16 + lo) * 64 + sw);
            __builtin_amdgcn_s_barrier();
            asm volatile("s_waitcnt lgkmcnt(0)" ::: "memory");
            __builtin_amdgcn_sched_barrier(0);
            __builtin_amdgcn_s_setprio(1);
            #pragma unroll
            for (int ii = 0; ii < 4; ++ii)
                #pragma unroll
                for (int jn = 0; jn < 2; ++jn)
                    acc[ii][jn] = __builtin_amdgcn_mfma_f32_16x16x32_bf16(af[ii], bf[jn], acc[ii][jn], 0, 0, 0);
            __builtin_amdgcn_s_setprio(0);
            __builtin_amdgcn_s_barrier();
            asm volatile("" ::: "memory");
        }
        if (kt + 2 < nkt) stage(kt + 2);
        if (kt + 1 < nkt) {
            if (kt + 2 < nkt) asm volatile("s_waitcnt vmcnt(4)" ::: "memory");
            else              asm volatile("s_waitcnt vmcnt(0)" ::: "memory");
            __builtin_amdgcn_s_barrier();
            asm volatile("" ::: "memory");
        }
    }

    #pragma unroll
    for (int ii = 0; ii < 4; ii++)
        #pragma unroll
        for (int r = 0; r < 4; r++) {
            int row = m0 + wm * 64 + ii * 16 + qd * 4 + r;
            float linv = 1.0f / Lb[row];
            #pragma unroll
            for (int jn = 0; jn < 2; jn++) {
                int col = n0 + wn * 32 + jn * 16 + lo;
                Ob[(size_t)row * DIM + col] = acc[ii][jn][r] * linv;
            }
        }
}

// ---------------------------------------------------------------------------
// Fallback path (small ws): gemm_legacy + flash_attn, unchanged.
// ---------------------------------------------------------------------------
__global__ __launch_bounds__(256) void gemm_legacy(
    const float* __restrict__ X,
    const float* __restrict__ Wq, const float* __restrict__ Wk, const float* __restrict__ Wv,
    u16* __restrict__ Qo, u16* __restrict__ Ko, u16* __restrict__ VTo)
{
    const int K = 1024, N = 1024;
    const float* W = (blockIdx.z == 0) ? Wq : (blockIdx.z == 1) ? Wk : Wv;
    int m0 = blockIdx.y * 128, n0 = blockIdx.x * 128;
    __shared__ __align__(16) u16 As[128 * 40];
    __shared__ __align__(16) u16 Bs[128 * 40];
    __shared__ __align__(16) u16 Ct[64][132];
    int tid = threadIdx.x, lane = tid & 63, w = tid >> 6;
    int wm = w >> 1, wn = w & 1, lo = lane & 15, qd = lane >> 4;
    fx4 acc[4][4] = {};
    for (int k0 = 0; k0 < K; k0 += 32) {
        #pragma unroll
        for (int c = tid; c < 1024; c += 256) {
            int row = c >> 3, cc = (c & 7) * 4;
            float4 v = *(const float4*)(X + (size_t)(m0 + row) * K + k0 + cc);
            uint2 pk;
            pk.x = (unsigned)f2bf(v.x) | ((unsigned)f2bf(v.y) << 16);
            pk.y = (unsigned)f2bf(v.z) | ((unsigned)f2bf(v.w) << 16);
            *(uint2*)(&As[row * 40 + cc]) = pk;
        }
        #pragma unroll
        for (int c = tid; c < 1024; c += 256) {
            int r = c >> 5, cc = (c & 31) * 4;
            float4 v = *(const float4*)(W + (size_t)(k0 + r) * N + n0 + cc);
            Bs[(cc + 0) * 40 + r] = f2bf(v.x);
            Bs[(cc + 1) * 40 + r] = f2bf(v.y);
            Bs[(cc + 2) * 40 + r] = f2bf(v.z);
            Bs[(cc + 3) * 40 + r] = f2bf(v.w);
        }
        __syncthreads();
        bfx8 af[4], bf[4];
        #pragma unroll
        for (int i = 0; i < 4; i++)
            af[i] = *(const bfx8*)(&As[(wm * 64 + i * 16 + lo) * 40 + qd * 8]);
        #pragma unroll
        for (int j = 0; j < 4; j++)
            bf[j] = *(const bfx8*)(&Bs[(wn * 64 + j * 16 + lo) * 40 + qd * 8]);
        #pragma unroll
        for (int i = 0; i < 4; i++)
            #pragma unroll
            for (int j = 0; j < 4; j++)
                acc[i][j] = __builtin_amdgcn_mfma_f32_16x16x32_bf16(af[i], bf[j], acc[i][j], 0, 0, 0);
        __syncthreads();
    }
    if (blockIdx.z != 2) {
        u16* C = (blockIdx.z == 0) ? Qo : Ko;
        #pragma unroll
        for (int i = 0; i < 4; i++)
            #pragma unroll
            for (int j = 0; j < 4; j++)
                #pragma unroll
                for (int r = 0; r < 4; r++) {
                    int row = m0 + wm * 64 + i * 16 + qd * 4 + r;
                    int col = n0 + wn * 64 + j * 16 + lo;
                    C[(size_t)row * N + col] = f2bf(acc[i][j][r]);
                }
    } else {
        #pragma unroll
        for (int half = 0; half < 2; half++) {
            __syncthreads();
            if (wm == half) {
                #pragma unroll
                for (int i = 0; i < 4; i++)
                    #pragma unroll
                    for (int j = 0; j < 4; j++)
                        #pragma unroll
                        for (int r = 0; r < 4; r++)
                            Ct[i * 16 + qd * 4 + r][wn * 64 + j * 16 + lo] = f2bf(acc[i][j][r]);
            }
            __syncthreads();
            #pragma unroll
            for (int e = tid; e < 64 * 128; e += 256) {
                int d = e >> 6, sl = e & 63;
                int gr = m0 + half * 64 + sl;
                int bb = gr >> 11, s = gr & 2047;
                VTo[((size_t)bb * DIM + (n0 + d)) * SEQ + s] = Ct[sl][d];
            }
        }
    }
}

__global__ __launch_bounds__(512) void flash_attn(
    const u16* __restrict__ Q, const u16* __restrict__ Kmat,
    const u16* __restrict__ VT, float* __restrict__ O)
{
    int b = blockIdx.y;
    int qt = (int)(gridDim.x - 1) - (int)blockIdx.x;
    int q0 = qt * 32;
    int tid = threadIdx.x;
    int lane = tid & 63, w = tid >> 6;
    int lo = lane & 15, qd = lane >> 4;

    __shared__ __align__(16) float Sp[8][32][33];
    __shared__ __align__(16) __bf16 Pl[32][40];
    __shared__ float ml[32], ll[32], al[32];

    const u16* Qb = Q + (size_t)b * SEQ * DIM;
    const u16* Kb = Kmat + (size_t)b * SEQ * DIM;
    const u16* VTb = VT + (size_t)b * DIM * SEQ;

    bfx8 qf[2][4];
    #pragma unroll
    for (int i = 0; i < 2; i++)
        #pragma unroll
        for (int c = 0; c < 4; c++)
            qf[i][c] = *(const bfx8*)(Qb + (size_t)(q0 + i * 16 + lo) * DIM + w * 128 + c * 32 + qd * 8);

    fx4 oacc[2][8] = {};
    if (tid < 32) { ml[tid] = -INFINITY; ll[tid] = 0.0f; }
    __syncthreads();

    for (int kt = 0; kt <= qt; kt++) {
        int k0 = kt * 32;
        fx4 sp[2][2] = {};
        #pragma unroll
        for (int c = 0; c < 4; c++) {
            bfx8 kf[2];
            #pragma unroll
            for (int jn = 0; jn < 2; jn++)
                kf[jn] = *(const bfx8*)(Kb + (size_t)(k0 + jn * 16 + lo) * DIM + w * 128 + c * 32 + qd * 8);
            #pragma unroll
            for (int i = 0; i < 2; i++)
                #pragma unroll
                for (int jn = 0; jn < 2; jn++)
                    sp[i][jn] = __builtin_amdgcn_mfma_f32_16x16x32_bf16(qf[i][c], kf[jn], sp[i][jn], 0, 0, 0);
        }
        #pragma unroll
        for (int i = 0; i < 2; i++)
            #pragma unroll
            for (int jn = 0; jn < 2; jn++)
                #pragma unroll
                for (int r = 0; r < 4; r++)
                    Sp[w][i * 16 + qd * 4 + r][jn * 16 + lo] = sp[i][jn][r];
        __syncthreads();
        {
            int r = tid >> 4, ci = tid & 15;
            int q = q0 + r;
            float s0 = 0.0f, s1 = 0.0f;
            #pragma unroll
            for (int p = 0; p < 8; p++) { s0 += Sp[p][r][ci]; s1 += Sp[p][r][ci + 16]; }
            s0 = fminf(fmaxf(s0 * SCALE, -1e30f), 1e30f);
            s1 = fminf(fmaxf(s1 * SCALE, -1e30f), 1e30f);
            if (k0 + ci > q)      s0 = -INFINITY;
            if (k0 + ci + 16 > q) s1 = -INFINITY;
            float mx = fmaxf(s0, s1);
            #pragma unroll
            for (int off = 1; off < 16; off <<= 1) mx = fmaxf(mx, __shfl_xor(mx, off));
            float mo = ml[r];
            float mn = fmaxf(mo, mx);
            float p0 = __expf(s0 - mn), p1 = __expf(s1 - mn);
            Pl[r][ci] = (__bf16)p0;
            Pl[r][ci + 16] = (__bf16)p1;
            float ps = p0 + p1;
            #pragma unroll
            for (int off = 1; off < 16; off <<= 1) ps += __shfl_xor(ps, off);
            if (ci == 0) {
                float alpha = __expf(mo - mn);
                ll[r] = alpha * ll[r] + ps;
                ml[r] = mn;
                al[r] = alpha;
            }
        }
        __syncthreads();
        float alocal[2][4];
        #pragma unroll
        for (int i = 0; i < 2; i++)
            #pragma unroll
            for (int r = 0; r < 4; r++)
                alocal[i][r] = al[i * 16 + qd * 4 + r];
        #pragma unroll
        for (int i = 0; i < 2; i++)
            #pragma unroll
            for (int j = 0; j < 8; j++)
                #pragma unroll
                for (int r = 0; r < 4; r++)
                    oacc[i][j][r] *= alocal[i][r];
        bfx8 pf[2];
        #pragma unroll
        for (int i = 0; i < 2; i++)
            pf[i] = *(const bfx8*)(&Pl[i * 16 + lo][qd * 8]);
        #pragma unroll
        for (int j = 0; j < 8; j++) {
            bfx8 vf = *(const bfx8*)(VTb + (size_t)(w * 128 + j * 16 + lo) * SEQ + k0 + qd * 8);
            #pragma unroll
            for (int i = 0; i < 2; i++)
                oacc[i][j] = __builtin_amdgcn_mfma_f32_16x16x32_bf16(pf[i], vf, oacc[i][j], 0, 0, 0);
        }
    }

    float linv[2][4];
    #pragma unroll
    for (int i = 0; i < 2; i++)
        #pragma unroll
        for (int r = 0; r < 4; r++)
            linv[i][r] = 1.0f / ll[i * 16 + qd * 4 + r];
    float* Ob = O + (size_t)b * SEQ * DIM;
    #pragma unroll
    for (int i = 0; i < 2; i++)
        #pragma unroll
        for (int j = 0; j < 8; j++)
            #pragma unroll
            for (int r = 0; r < 4; r++) {
                int row = q0 + i * 16 + qd * 4 + r;
                int col = w * 128 + j * 16 + lo;
                Ob[(size_t)row * DIM + col] = oacc[i][j][r] * linv[i][r];
            }
}

// ---------------------------------------------------------------------------
extern "C" void kernel_launch(void* const* d_in, const int* in_sizes, int n_in,
                              void* d_out, int out_size, void* d_ws, size_t ws_size,
                              hipStream_t stream) {
    const float* x  = (const float*)d_in[0];
    const float* Wq = (const float*)d_in[1];
    const float* Wk = (const float*)d_in[2];
    const float* Wv = (const float*)d_in[3];

    u16* ws = (u16*)d_ws;
    // mat-path layout: Y, VT, XB, WB(q,k straight), WTv, MT, P, Lrow
    u16* Yp  = ws;                                   // NEL (16 MiB)
    u16* VTp = ws + NEL;                             // NEL
    u16* XBp = ws + 2 * NEL;                         // NEL
    u16* WBp = ws + 3 * NEL;                         // 2 MiElem (4 MiB)
    u16* WTv = WBp + (size_t)2 * 1024 * 1024;        // 1 MiElem (2 MiB)
    u16* MTp = WTv + (size_t)1024 * 1024;            // 1 MiElem (2 MiB)
    u16* Pm  = MTp + (size_t)1024 * 1024;            // 4*SEQ*SEQ (33.6 MiB)
    float* Lrow = (float*)(Pm + (size_t)NBATCH * SEQ * SEQ);

    size_t need_mat = ((size_t)3 * NEL + (size_t)4 * 1024 * 1024
                     + (size_t)NBATCH * SEQ * SEQ) * 2
                     + (size_t)NBATCH * SEQ * 4 + 1024;   // ~92.3 MiB

    if (ws_size >= need_mat) {
        prep<<<dim3(11296), 256, 0, stream>>>(x, Wq, Wk, Wv, XBp, WBp, WTv, Lrow);
        gemm_m<<<dim3(8, 8), 256, 0, stream>>>(
            WBp + (size_t)1024 * 1024 /*WBk*/, WBp /*WBq*/, MTp);
        gemm256<<<dim3(256), 1024, 0, stream>>>(XBp, MTp, WTv, Yp, VTp);
        sgemm_exp<<<dim3(544), 512, 0, stream>>>(Yp, XBp, Pm, Lrow);
        pvgemm<<<dim3(512), 512, 0, stream>>>(Pm, VTp, Lrow, (float*)d_out);
    } else {
        u16* Qp = ws; u16* Kp = ws + NEL; u16* VTf = ws + 2 * NEL;
        gemm_legacy<<<dim3(8, 64, 3), 256, 0, stream>>>(x, Wq, Wk, Wv, Qp, Kp, VTf);
        flash_attn<<<dim3(SEQ / 32, NBATCH), 512, 0, stream>>>(
            Qp, Kp, VTf, (float*)d_out);
    }
}

// Round 6
// 207.425 us; speedup vs baseline: 1.0466x; 1.0466x over previous
//
#include <hip/hip_runtime.h>
#include <hip/hip_bf16.h>

typedef unsigned short u16;
typedef __bf16 bfx8 __attribute__((ext_vector_type(8)));
typedef float fx4 __attribute__((ext_vector_type(4)));

#define SEQ 2048
#define DIM 1024
#define NBATCH 4
#define SCALE 0.03125f  // 1/sqrt(1024)
#define NEL ((size_t)NBATCH * SEQ * DIM)   // 8388608 elems per Q/K/V

__device__ inline u16 f2bf(float f) {
    __bf16 h = (__bf16)f;
    return __builtin_bit_cast(unsigned short, h);
}

// async global->LDS, 16B per lane (dst must be wave-uniform base + lane*16;
// padding the LDS row stride is NOT possible -> xor-swizzle the SOURCE chunk)
#define GLL(gp, lp) __builtin_amdgcn_global_load_lds( \
    (const __attribute__((address_space(1))) unsigned int*)(gp), \
    (__attribute__((address_space(3))) unsigned int*)(lp), 16, 0, 0)

// ---------------------------------------------------------------------------
// prep: blocks [0,8192): convert x -> XB (bf16)
//       blocks [8192,10240): straight-convert Wq,Wk -> WBq,WBk
//       blocks [10240,11264): transpose Wv -> WTv[e][d]
//       blocks [11264,11296): zero Lrow
// ---------------------------------------------------------------------------
__global__ __launch_bounds__(256) void prep(
    const float* __restrict__ X,
    const float* __restrict__ Wq, const float* __restrict__ Wk,
    const float* __restrict__ Wv,
    u16* __restrict__ XB, u16* __restrict__ WB, u16* __restrict__ WTv,
    float* __restrict__ Lrow)
{
    __shared__ u16 t[32][33];
    int bid = blockIdx.x;
    int tid = threadIdx.x;
    if (bid < 8192) {
        size_t i = (size_t)bid * 256 + tid;
        float4 v = ((const float4*)X)[i];
        uint2 pk;
        pk.x = (unsigned)f2bf(v.x) | ((unsigned)f2bf(v.y) << 16);
        pk.y = (unsigned)f2bf(v.z) | ((unsigned)f2bf(v.w) << 16);
        ((uint2*)XB)[i] = pk;
    } else if (bid < 10240) {
        int b2 = bid - 8192;                       // 0..2047
        const float* W = (b2 < 1024) ? Wq : Wk;
        u16* out = WB + (size_t)(b2 >> 10) * 1024 * 1024;
        size_t i = (size_t)(b2 & 1023) * 256 + tid;  // float4 units
        float4 v = ((const float4*)W)[i];
        uint2 pk;
        pk.x = (unsigned)f2bf(v.x) | ((unsigned)f2bf(v.y) << 16);
        pk.y = (unsigned)f2bf(v.z) | ((unsigned)f2bf(v.w) << 16);
        ((uint2*)out)[i] = pk;
    } else if (bid < 11264) {
        int t2 = bid - 10240;                      // 0..1023 tiles
        int n0 = (t2 & 31) * 32, k0 = (t2 >> 5) * 32;
        int tx = tid & 31, ty = tid >> 5;
        #pragma unroll
        for (int i = 0; i < 32; i += 8)
            t[ty + i][tx] = f2bf(Wv[(size_t)(k0 + ty + i) * 1024 + n0 + tx]);
        __syncthreads();
        #pragma unroll
        for (int i = 0; i < 32; i += 8)
            WTv[(size_t)(n0 + ty + i) * 1024 + k0 + tx] = t[tx][ty + i];
    } else {
        int i = (bid - 11264) * 256 + tid;   // 8192 floats
        Lrow[i] = 0.0f;
    }
}

// ---------------------------------------------------------------------------
// gemm_m: MT[d2][d1] = sum_e WBk[d2][e] * WBq[d1][e].  Grid (8,8), small.
// ---------------------------------------------------------------------------
__global__ __launch_bounds__(256) void gemm_m(
    const u16* __restrict__ WBk, const u16* __restrict__ WBq, u16* __restrict__ MT)
{
    int m0 = blockIdx.y * 128, n0 = blockIdx.x * 128;
    __shared__ __align__(16) u16 As[128 * 32];
    __shared__ __align__(16) u16 Bs[128 * 32];
    int tid = threadIdx.x, lane = tid & 63, w = tid >> 6;
    int wm = w >> 1, wn = w & 1, lo = lane & 15, qd = lane >> 4;
    fx4 acc[4][4] = {};

    int c0 = tid, c1 = tid + 256;
    const u16* a0 = WBk + (size_t)(m0 + (c0 >> 2)) * 1024 + (((c0 & 3) ^ ((c0 >> 2) & 3)) * 8);
    const u16* a1 = WBk + (size_t)(m0 + (c1 >> 2)) * 1024 + (((c1 & 3) ^ ((c1 >> 2) & 3)) * 8);
    const u16* b0 = WBq + (size_t)(n0 + (c0 >> 2)) * 1024 + (((c0 & 3) ^ ((c0 >> 2) & 3)) * 8);
    const u16* b1 = WBq + (size_t)(n0 + (c1 >> 2)) * 1024 + (((c1 & 3) ^ ((c1 >> 2) & 3)) * 8);

    int sw = (qd ^ (lo & 3)) * 8;
    for (int k0 = 0; k0 < 1024; k0 += 32) {
        GLL(a0 + k0, &As[(size_t)c0 * 8]);
        GLL(a1 + k0, &As[(size_t)c1 * 8]);
        GLL(b0 + k0, &Bs[(size_t)c0 * 8]);
        GLL(b1 + k0, &Bs[(size_t)c1 * 8]);
        __syncthreads();
        bfx8 af[4], bf[4];
        #pragma unroll
        for (int i = 0; i < 4; i++)
            af[i] = *(const bfx8*)(&As[(wm * 64 + i * 16 + lo) * 32 + sw]);
        #pragma unroll
        for (int j = 0; j < 4; j++)
            bf[j] = *(const bfx8*)(&Bs[(wn * 64 + j * 16 + lo) * 32 + sw]);
        #pragma unroll
        for (int i = 0; i < 4; i++)
            #pragma unroll
            for (int j = 0; j < 4; j++)
                acc[i][j] = __builtin_amdgcn_mfma_f32_16x16x32_bf16(af[i], bf[j], acc[i][j], 0, 0, 0);
        __syncthreads();
    }
    #pragma unroll
    for (int i = 0; i < 4; i++)
        #pragma unroll
        for (int j = 0; j < 4; j++)
            #pragma unroll
            for (int r = 0; r < 4; r++)
                MT[(size_t)(m0 + wm * 64 + i * 16 + qd * 4 + r) * 1024
                   + n0 + wn * 64 + j * 16 + lo] = f2bf(acc[i][j][r]);
}

// ---------------------------------------------------------------------------
// gemm256: z=0: Y = XB x MT^T; z=1: V = XB x WTv^T stored TRANSPOSED.
// r6: faithful m201 8-phase port.  512 thr / 8 waves (2m x 4n), per-wave
// 128x64 (acc[8][4]).  256x256 tile, BK=64, dbuf 128 KiB.  Per K-tile: 4
// quadrant phases, each = {quadrant ds_reads || stage ONE 16KB half-tile
// (2 GLL) -> lgkmcnt(8) -> barrier -> lgkmcnt(0) -> setprio(1) -> 16 MFMA
// -> setprio(0) -> barrier}.  Stage order (write-after-read safe, derived):
// ph0: A-m1(kt+1), ph1: B-n1(kt+1), ph2: A-m0(kt+2), ph3: B-n0(kt+2).
// One vmcnt(4)+barrier per K-tile boundary (only kt+2's 2 half-tiles in
// flight; every staged load gets >=3 phases of latency cover).
// XCD-chunked grid mapping (r4, FETCH 103->24.7 MB verified).
// ---------------------------------------------------------------------------
__global__ __launch_bounds__(512) void gemm256(
    const u16* __restrict__ XB, const u16* __restrict__ MT,
    const u16* __restrict__ WTv,
    u16* __restrict__ Yo, u16* __restrict__ VTo)
{
    const int work = ((blockIdx.x & 7) << 5) + ((int)blockIdx.x >> 3);
    const int z = work >> 7;                 // 0..1
    const int m0 = ((work >> 2) & 31) * 256; // 32 m-blocks
    const int n0 = (work & 3) * 256;         // 4 n-blocks
    const u16* Bop = (z == 0) ? MT : WTv;

    // A: [0,16384) buf0, [16384,32768) buf1
    // B: [32768,49152) buf0, [49152,65536) buf1        (u16 elements)
    __shared__ __align__(16) u16 SM[65536];   // 128 KiB

    const int tid = threadIdx.x, lane = tid & 63, w = tid >> 6;
    const int wm = w >> 2, wn = w & 3, lo = lane & 15, qd = lane >> 4;
    const int swl = lo & 7;

    fx4 acc[8][4] = {};

    // half-tile staging: half h = rows [h*128, h*128+128) of the 256-row tile;
    // one half-tile = 16 KB = 512 thr x 1 GLL x ... 2 GLL per thread? no:
    // 128 rows x 8 chunks = 1024 chunks; 512 threads -> 2 chunks (p=0,1).
    const u16* sA[2][2]; const u16* sB[2][2]; int dofs[2][2];
    #pragma unroll
    for (int h = 0; h < 2; ++h)
        #pragma unroll
        for (int p = 0; p < 2; ++p) {
            int n = p * 512 + tid;                 // 0..1023 within half
            int rl = n >> 3;                       // local row 0..127
            int c = (n & 7) ^ (rl & 7);            // pre-swizzled source chunk
            sA[h][p] = XB  + (size_t)(m0 + h * 128 + rl) * 1024 + c * 8;
            sB[h][p] = Bop + (size_t)(n0 + h * 128 + rl) * 1024 + c * 8;
            dofs[h][p] = (h * 1024 + n) * 8;       // linear LDS dest (u16)
        }

    auto stageA = [&](int kt2, int h) {
        const int bb = (kt2 & 1) * 16384;
        GLL(sA[h][0] + kt2 * 64, &SM[bb + dofs[h][0]]);
        GLL(sA[h][1] + kt2 * 64, &SM[bb + dofs[h][1]]);
    };
    auto stageB = [&](int kt2, int h) {
        const int bb = 32768 + (kt2 & 1) * 16384;
        GLL(sB[h][0] + kt2 * 64, &SM[bb + dofs[h][0]]);
        GLL(sB[h][1] + kt2 * 64, &SM[bb + dofs[h][1]]);
    };

    // prologue: kt0 full (8 GLL) + kt1 {A-m0, B-n0} (4 GLL); wait kt0.
    stageA(0, 0); stageA(0, 1); stageB(0, 0); stageB(0, 1);
    stageA(1, 0); stageB(1, 0);
    asm volatile("s_waitcnt vmcnt(4)" ::: "memory");
    __builtin_amdgcn_s_barrier();
    asm volatile("" ::: "memory");

    #pragma unroll 2
    for (int kt = 0; kt < 16; ++kt) {
        const u16* Ab = SM + (kt & 1) * 16384;
        const u16* Bb = SM + 32768 + (kt & 1) * 16384;

        bfx8 af[4][2], b0r[2][2], b1r[2][2];

        // ---- phase 0: quadrant (m0,n0) — reads A-m0(8) + B-n0(4); stage A-m1(kt+1)
        #pragma unroll
        for (int ii = 0; ii < 4; ++ii)
            #pragma unroll
            for (int ks = 0; ks < 2; ++ks)
                af[ii][ks] = *(const bfx8*)(Ab + (wm * 128 + ii * 16 + lo) * 64
                                            + ((ks * 4 + qd) ^ swl) * 8);
        #pragma unroll
        for (int jn = 0; jn < 2; ++jn)
            #pragma unroll
            for (int ks = 0; ks < 2; ++ks)
                b0r[jn][ks] = *(const bfx8*)(Bb + (wn * 64 + jn * 16 + lo) * 64
                                             + ((ks * 4 + qd) ^ swl) * 8);
        if (kt < 15) stageA(kt + 1, 1);
        asm volatile("s_waitcnt lgkmcnt(8)" ::: "memory");
        __builtin_amdgcn_s_barrier();
        asm volatile("s_waitcnt lgkmcnt(0)" ::: "memory");
        __builtin_amdgcn_sched_barrier(0);
        __builtin_amdgcn_s_setprio(1);
        #pragma unroll
        for (int ii = 0; ii < 4; ++ii)
            #pragma unroll
            for (int jn = 0; jn < 2; ++jn)
                #pragma unroll
                for (int ks = 0; ks < 2; ++ks)
                    acc[ii][jn] = __builtin_amdgcn_mfma_f32_16x16x32_bf16(
                        af[ii][ks], b0r[jn][ks], acc[ii][jn], 0, 0, 0);
        __builtin_amdgcn_s_setprio(0);
        __builtin_amdgcn_s_barrier();
        asm volatile("" ::: "memory");

        // ---- phase 1: quadrant (m0,n1) — reads B-n1(4); stage B-n1(kt+1)
        #pragma unroll
        for (int jn = 0; jn < 2; ++jn)
            #pragma unroll
            for (int ks = 0; ks < 2; ++ks)
                b1r[jn][ks] = *(const bfx8*)(Bb + (wn * 64 + (2 + jn) * 16 + lo) * 64
                                             + ((ks * 4 + qd) ^ swl) * 8);
        if (kt < 15) stageB(kt + 1, 1);
        __builtin_amdgcn_s_barrier();
        asm volatile("s_waitcnt lgkmcnt(0)" ::: "memory");
        __builtin_amdgcn_sched_barrier(0);
        __builtin_amdgcn_s_setprio(1);
        #pragma unroll
        for (int ii = 0; ii < 4; ++ii)
            #pragma unroll
            for (int jn = 0; jn < 2; ++jn)
                #pragma unroll
                for (int ks = 0; ks < 2; ++ks)
                    acc[ii][2 + jn] = __builtin_amdgcn_mfma_f32_16x16x32_bf16(
                        af[ii][ks], b1r[jn][ks], acc[ii][2 + jn], 0, 0, 0);
        __builtin_amdgcn_s_setprio(0);
        __builtin_amdgcn_s_barrier();
        asm volatile("" ::: "memory");

        // ---- phase 2: quadrant (m1,n0) — reads A-m1(8); stage A-m0(kt+2)
        #pragma unroll
        for (int ii = 0; ii < 4; ++ii)
            #pragma unroll
            for (int ks = 0; ks < 2; ++ks)
                af[ii][ks] = *(const bfx8*)(Ab + (wm * 128 + (4 + ii) * 16 + lo) * 64
                                            + ((ks * 4 + qd) ^ swl) * 8);
        if (kt < 14) stageA(kt + 2, 0);
        __builtin_amdgcn_s_barrier();
        asm volatile("s_waitcnt lgkmcnt(0)" ::: "memory");
        __builtin_amdgcn_sched_barrier(0);
        __builtin_amdgcn_s_setprio(1);
        #pragma unroll
        for (int ii = 0; ii < 4; ++ii)
            #pragma unroll
            for (int jn = 0; jn < 2; ++jn)
                #pragma unroll
                for (int ks = 0; ks < 2; ++ks)
                    acc[4 + ii][jn] = __builtin_amdgcn_mfma_f32_16x16x32_bf16(
                        af[ii][ks], b0r[jn][ks], acc[4 + ii][jn], 0, 0, 0);
        __builtin_amdgcn_s_setprio(0);
        __builtin_amdgcn_s_barrier();
        asm volatile("" ::: "memory");

        // ---- phase 3: quadrant (m1,n1) — no reads; stage B-n0(kt+2)
        if (kt < 14) stageB(kt + 2, 0);
        __builtin_amdgcn_s_barrier();
        __builtin_amdgcn_sched_barrier(0);
        __builtin_amdgcn_s_setprio(1);
        #pragma unroll
        for (int ii = 0; ii < 4; ++ii)
            #pragma unroll
            for (int jn = 0; jn < 2; ++jn)
                #pragma unroll
                for (int ks = 0; ks < 2; ++ks)
                    acc[4 + ii][2 + jn] = __builtin_amdgcn_mfma_f32_16x16x32_bf16(
                        af[ii][ks], b1r[jn][ks], acc[4 + ii][2 + jn], 0, 0, 0);
        __builtin_amdgcn_s_setprio(0);
        __builtin_amdgcn_s_barrier();
        asm volatile("" ::: "memory");

        // ---- K-tile boundary: kt+1's data (issued >= 3 phases ago) must land;
        // only kt+2's A-m0/B-n0 (4 GLL, just issued) may stay in flight.
        if (kt < 15) {
            if (kt < 14) asm volatile("s_waitcnt vmcnt(4)" ::: "memory");
            else         asm volatile("s_waitcnt vmcnt(0)" ::: "memory");
            __builtin_amdgcn_s_barrier();
            asm volatile("" ::: "memory");
        }
    }

    if (z == 0) {
        #pragma unroll
        for (int i = 0; i < 8; i++)
            #pragma unroll
            for (int j = 0; j < 4; j++)
                #pragma unroll
                for (int r = 0; r < 4; r++) {
                    int row = m0 + wm * 128 + i * 16 + qd * 4 + r;
                    int col = n0 + wn * 64 + j * 16 + lo;
                    Yo[(size_t)row * 1024 + col] = f2bf(acc[i][j][r]);
                }
    } else {
        u16 (*Ct)[258] = (u16(*)[258])SM;
        const int bb = m0 >> 11;          // batch (tiles never straddle)
        const int sbase = m0 & 2047;
        #pragma unroll
        for (int half = 0; half < 2; ++half) {
            __syncthreads();
            if (wm == half) {
                #pragma unroll
                for (int i = 0; i < 8; i++)
                    #pragma unroll
                    for (int j = 0; j < 4; j++)
                        #pragma unroll
                        for (int r = 0; r < 4; r++)
                            Ct[i * 16 + qd * 4 + r][wn * 64 + j * 16 + lo] = f2bf(acc[i][j][r]);
            }
            __syncthreads();
            for (int e = tid; e < 16384; e += 512) {
                int d = e >> 6, s2 = (e & 63) * 2;
                unsigned pk = (unsigned)Ct[s2][d] | ((unsigned)Ct[s2 + 1][d] << 16);
                *(unsigned*)&VTo[((size_t)bb * DIM + (n0 + d)) * SEQ
                                 + sbase + half * 128 + s2] = pk;
            }
        }
    }
}

// ---------------------------------------------------------------------------
// sgemm_exp: P = exp(scale*(Y x XB^T) masked), causal 128x128 tiles, bf16,
// UNNORMALIZED (clamped +-30).  Row sums -> atomicAdd.
// r4: XCD-chunked mapping (verified: FETCH dedup'd), 64 KiB dbuf pipeline.
// ---------------------------------------------------------------------------
__global__ __launch_bounds__(512) void sgemm_exp(
    const u16* __restrict__ Y, const u16* __restrict__ XB,
    u16* __restrict__ P, float* __restrict__ Lrow)
{
    const int k = blockIdx.x;                       // 0..543 (= 8 * 68)
    const int work = (k & 7) * 68 + (k >> 3);       // XCD-contiguous
    const int b = work / 136;
    const int t = work % 136;                       // triangular tile
    int i = (int)((sqrtf(8.0f * t + 1.0f) - 1.0f) * 0.5f);
    while ((i + 1) * (i + 2) / 2 <= t) i++;
    while (i * (i + 1) / 2 > t) i--;
    int j = t - i * (i + 1) / 2;

    const u16* Yb = Y + (size_t)b * SEQ * DIM;
    const u16* Xb = XB + (size_t)b * SEQ * DIM;
    u16* Pb = P + (size_t)b * SEQ * SEQ;
    float* Lb = Lrow + (size_t)b * SEQ;

    int m0 = i * 128, n0 = j * 128;

    // A0 [0,8192) A1 [8192,16384) B0 [16384,24576) B1 [24576,32768)  (u16)
    __shared__ __align__(16) u16 SM[32768];   // 64 KiB

    int tid = threadIdx.x, lane = tid & 63, w = tid >> 6;
    int wm = w >> 2, wn = w & 3, lo = lane & 15, qd = lane >> 4;
    int swl = lo & 7;

    fx4 acc[4][2] = {};

    int c0 = tid, c1 = tid + 512;        // 1024 chunks of 16B per operand
    const u16* a0 = Yb + (size_t)(m0 + (c0 >> 3)) * 1024 + (((c0 & 7) ^ ((c0 >> 3) & 7)) * 8);
    const u16* a1 = Yb + (size_t)(m0 + (c1 >> 3)) * 1024 + (((c1 & 7) ^ ((c1 >> 3) & 7)) * 8);
    const u16* b0 = Xb + (size_t)(n0 + (c0 >> 3)) * 1024 + (((c0 & 7) ^ ((c0 >> 3) & 7)) * 8);
    const u16* b1 = Xb + (size_t)(n0 + (c1 >> 3)) * 1024 + (((c1 & 7) ^ ((c1 >> 3) & 7)) * 8);
    int d0 = c0 * 8, d1 = c1 * 8;

    auto stage = [&](int kt2) {
        int bb = (kt2 & 1) * 8192;
        GLL(a0 + kt2 * 64, &SM[bb + d0]);
        GLL(a1 + kt2 * 64, &SM[bb + d1]);
        GLL(b0 + kt2 * 64, &SM[16384 + bb + d0]);
        GLL(b1 + kt2 * 64, &SM[16384 + bb + d1]);
    };

    stage(0);
    stage(1);
    asm volatile("s_waitcnt vmcnt(4)" ::: "memory");
    __builtin_amdgcn_s_barrier();
    asm volatile("" ::: "memory");

    for (int kt = 0; kt < 16; ++kt) {
        const u16* Ab = SM + (kt & 1) * 8192;
        const u16* Bb = SM + 16384 + (kt & 1) * 8192;

        #pragma unroll
        for (int kc = 0; kc < 2; ++kc) {
            bfx8 af[4], bf[2];
            int sw = ((kc * 4 + qd) ^ swl) * 8;
            #pragma unroll
            for (int ii = 0; ii < 4; ++ii)
                af[ii] = *(const bfx8*)(Ab + (wm * 64 + ii * 16 + lo) * 64 + sw);
            #pragma unroll
            for (int jn = 0; jn < 2; ++jn)
                bf[jn] = *(const bfx8*)(Bb + (wn * 32 + jn * 16 + lo) * 64 + sw);
            __builtin_amdgcn_s_barrier();
            asm volatile("s_waitcnt lgkmcnt(0)" ::: "memory");
            __builtin_amdgcn_sched_barrier(0);
            __builtin_amdgcn_s_setprio(1);
            #pragma unroll
            for (int ii = 0; ii < 4; ++ii)
                #pragma unroll
                for (int jn = 0; jn < 2; ++jn)
                    acc[ii][jn] = __builtin_amdgcn_mfma_f32_16x16x32_bf16(af[ii], bf[jn], acc[ii][jn], 0, 0, 0);
            __builtin_amdgcn_s_setprio(0);
            __builtin_amdgcn_s_barrier();
            asm volatile("" ::: "memory");
        }
        if (kt < 14) stage(kt + 2);
        if (kt < 15) {
            if (kt < 14) asm volatile("s_waitcnt vmcnt(4)" ::: "memory");
            else         asm volatile("s_waitcnt vmcnt(0)" ::: "memory");
            __builtin_amdgcn_s_barrier();
            asm volatile("" ::: "memory");
        }
    }

    #pragma unroll
    for (int ii = 0; ii < 4; ii++)
        #pragma unroll
        for (int r = 0; r < 4; r++) {
            int row = m0 + wm * 64 + ii * 16 + qd * 4 + r;
            float rs = 0.0f;
            #pragma unroll
            for (int jn = 0; jn < 2; jn++) {
                int col = n0 + wn * 32 + jn * 16 + lo;
                float s = acc[ii][jn][r] * SCALE;
                s = fminf(fmaxf(s, -30.0f), 30.0f);
                float p = (col > row) ? 0.0f : __expf(s);
                Pb[(size_t)row * SEQ + col] = f2bf(p);
                rs += p;
            }
            #pragma unroll
            for (int off = 1; off < 16; off <<= 1) rs += __shfl_xor(rs, off);
            if (lo == 0) atomicAdd(&Lb[row], rs);
        }
}

// ---------------------------------------------------------------------------
// pvgemm: O[q][d] = P[q][k] x VT[d][k] / L[q].  128x128 tiles, variable
// nkt = 2(qb+1).  r4: XCD-chunked + work-balanced qb-sets (verified).
// ---------------------------------------------------------------------------
__global__ __launch_bounds__(512) void pvgemm(
    const u16* __restrict__ P, const u16* __restrict__ VT,
    const float* __restrict__ Lrow, float* __restrict__ O)
{
    const int k = blockIdx.x;                 // 0..511 (= 8 * 64)
    const int xcd = k & 7, slot = k >> 3;     // slot 0..63
    const int b = xcd >> 1, half = xcd & 1;
    const int qsel = slot >> 3, db = slot & 7;
    const int qb = half ? (11 - qsel)
                        : ((qsel < 4) ? (15 - qsel) : (7 - qsel));
    int m0 = qb * 128, n0 = db * 128;
    int nkt = (qb + 1) * 2;                   // K-tiles of 64, >= 2

    const u16* Pb = P + (size_t)b * SEQ * SEQ;
    const u16* Vb = VT + (size_t)b * DIM * SEQ;
    const float* Lb = Lrow + (size_t)b * SEQ;
    float* Ob = O + (size_t)b * SEQ * DIM;

    // A0 [0,8192) A1 [8192,16384) B0 [16384,24576) B1 [24576,32768)  (u16)
    __shared__ __align__(16) u16 SM[32768];   // 64 KiB

    int tid = threadIdx.x, lane = tid & 63, w = tid >> 6;
    int wm = w >> 2, wn = w & 3, lo = lane & 15, qd = lane >> 4;
    int swl = lo & 7;

    fx4 acc[4][2] = {};

    int c0 = tid, c1 = tid + 512;
    const u16* a0 = Pb + (size_t)(m0 + (c0 >> 3)) * SEQ + (((c0 & 7) ^ ((c0 >> 3) & 7)) * 8);
    const u16* a1 = Pb + (size_t)(m0 + (c1 >> 3)) * SEQ + (((c1 & 7) ^ ((c1 >> 3) & 7)) * 8);
    const u16* b0 = Vb + (size_t)(n0 + (c0 >> 3)) * SEQ + (((c0 & 7) ^ ((c0 >> 3) & 7)) * 8);
    const u16* b1 = Vb + (size_t)(n0 + (c1 >> 3)) * SEQ + (((c1 & 7) ^ ((c1 >> 3) & 7)) * 8);
    int d0 = c0 * 8, d1 = c1 * 8;

    auto stage = [&](int kt2) {
        int bb = (kt2 & 1) * 8192;
        GLL(a0 + kt2 * 64, &SM[bb + d0]);
        GLL(a1 + kt2 * 64, &SM[bb + d1]);
        GLL(b0 + kt2 * 64, &SM[16384 + bb + d0]);
        GLL(b1 + kt2 * 64, &SM[16384 + bb + d1]);
    };

    stage(0);
    stage(1);                                // nkt >= 2 always
    asm volatile("s_waitcnt vmcnt(4)" ::: "memory");
    __builtin_amdgcn_s_barrier();
    asm volatile("" ::: "memory");

    for (int kt = 0; kt < nkt; ++kt) {
        const u16* Ab = SM + (kt & 1) * 8192;
        const u16* Bb = SM + 16384 + (kt & 1) * 8192;

        #pragma unroll
        for (int kc = 0; kc < 2; ++kc) {
            bfx8 af[4], bf[2];
            int sw = ((kc * 4 + qd) ^ swl) * 8;
            #pragma unroll
            for (int ii = 0; ii < 4; ++ii)
                af[ii] = *(const bfx8*)(Ab + (wm * 64 + ii * 16 + lo) * 64 + sw);
            #pragma unroll
            for (int jn = 0; jn < 2; ++jn)
                bf[jn] = *(const bfx8*)(Bb + (wn * 32 + jn * 16 + lo) * 64 + sw);
            __builtin_amdgcn_s_barrier();
            asm volatile("s_waitcnt lgkmcnt(0)" ::: "memory");
            __builtin_amdgcn_sched_barrier(0);
            __builtin_amdgcn_s_setprio(1);
            #pragma unroll
            for (int ii = 0; ii < 4; ++ii)
                #pragma unroll
                for (int jn = 0; jn < 2; ++jn)
                    acc[ii][jn] = __builtin_amdgcn_mfma_f32_16x16x32_bf16(af[ii], bf[jn], acc[ii][jn], 0, 0, 0);
            __builtin_amdgcn_s_setprio(0);
            __builtin_amdgcn_s_barrier();
            asm volatile("" ::: "memory");
        }
        if (kt + 2 < nkt) stage(kt + 2);
        if (kt + 1 < nkt) {
            if (kt + 2 < nkt) asm volatile("s_waitcnt vmcnt(4)" ::: "memory");
            else              asm volatile("s_waitcnt vmcnt(0)" ::: "memory");
            __builtin_amdgcn_s_barrier();
            asm volatile("" ::: "memory");
        }
    }

    #pragma unroll
    for (int ii = 0; ii < 4; ii++)
        #pragma unroll
        for (int r = 0; r < 4; r++) {
            int row = m0 + wm * 64 + ii * 16 + qd * 4 + r;
            float linv = 1.0f / Lb[row];
            #pragma unroll
            for (int jn = 0; jn < 2; jn++) {
                int col = n0 + wn * 32 + jn * 16 + lo;
                Ob[(size_t)row * DIM + col] = acc[ii][jn][r] * linv;
            }
        }
}

// ---------------------------------------------------------------------------
// Fallback path (small ws): gemm_legacy + flash_attn, unchanged.
// ---------------------------------------------------------------------------
__global__ __launch_bounds__(256) void gemm_legacy(
    const float* __restrict__ X,
    const float* __restrict__ Wq, const float* __restrict__ Wk, const float* __restrict__ Wv,
    u16* __restrict__ Qo, u16* __restrict__ Ko, u16* __restrict__ VTo)
{
    const int K = 1024, N = 1024;
    const float* W = (blockIdx.z == 0) ? Wq : (blockIdx.z == 1) ? Wk : Wv;
    int m0 = blockIdx.y * 128, n0 = blockIdx.x * 128;
    __shared__ __align__(16) u16 As[128 * 40];
    __shared__ __align__(16) u16 Bs[128 * 40];
    __shared__ __align__(16) u16 Ct[64][132];
    int tid = threadIdx.x, lane = tid & 63, w = tid >> 6;
    int wm = w >> 1, wn = w & 1, lo = lane & 15, qd = lane >> 4;
    fx4 acc[4][4] = {};
    for (int k0 = 0; k0 < K; k0 += 32) {
        #pragma unroll
        for (int c = tid; c < 1024; c += 256) {
            int row = c >> 3, cc = (c & 7) * 4;
            float4 v = *(const float4*)(X + (size_t)(m0 + row) * K + k0 + cc);
            uint2 pk;
            pk.x = (unsigned)f2bf(v.x) | ((unsigned)f2bf(v.y) << 16);
            pk.y = (unsigned)f2bf(v.z) | ((unsigned)f2bf(v.w) << 16);
            *(uint2*)(&As[row * 40 + cc]) = pk;
        }
        #pragma unroll
        for (int c = tid; c < 1024; c += 256) {
            int r = c >> 5, cc = (c & 31) * 4;
            float4 v = *(const float4*)(W + (size_t)(k0 + r) * N + n0 + cc);
            Bs[(cc + 0) * 40 + r] = f2bf(v.x);
            Bs[(cc + 1) * 40 + r] = f2bf(v.y);
            Bs[(cc + 2) * 40 + r] = f2bf(v.z);
            Bs[(cc + 3) * 40 + r] = f2bf(v.w);
        }
        __syncthreads();
        bfx8 af[4], bf[4];
        #pragma unroll
        for (int i = 0; i < 4; i++)
            af[i] = *(const bfx8*)(&As[(wm * 64 + i * 16 + lo) * 40 + qd * 8]);
        #pragma unroll
        for (int j = 0; j < 4; j++)
            bf[j] = *(const bfx8*)(&Bs[(wn * 64 + j * 16 + lo) * 40 + qd * 8]);
        #pragma unroll
        for (int i = 0; i < 4; i++)
            #pragma unroll
            for (int j = 0; j < 4; j++)
                acc[i][j] = __builtin_amdgcn_mfma_f32_16x16x32_bf16(af[i], bf[j], acc[i][j], 0, 0, 0);
        __syncthreads();
    }
    if (blockIdx.z != 2) {
        u16* C = (blockIdx.z == 0) ? Qo : Ko;
        #pragma unroll
        for (int i = 0; i < 4; i++)
            #pragma unroll
            for (int j = 0; j < 4; j++)
                #pragma unroll
                for (int r = 0; r < 4; r++) {
                    int row = m0 + wm * 64 + i * 16 + qd * 4 + r;
                    int col = n0 + wn * 64 + j * 16 + lo;
                    C[(size_t)row * N + col] = f2bf(acc[i][j][r]);
                }
    } else {
        #pragma unroll
        for (int half = 0; half < 2; half++) {
            __syncthreads();
            if (wm == half) {
                #pragma unroll
                for (int i = 0; i < 4; i++)
                    #pragma unroll
                    for (int j = 0; j < 4; j++)
                        #pragma unroll
                        for (int r = 0; r < 4; r++)
                            Ct[i * 16 + qd * 4 + r][wn * 64 + j * 16 + lo] = f2bf(acc[i][j][r]);
            }
            __syncthreads();
            #pragma unroll
            for (int e = tid; e < 64 * 128; e += 256) {
                int d = e >> 6, sl = e & 63;
                int gr = m0 + half * 64 + sl;
                int bb = gr >> 11, s = gr & 2047;
                VTo[((size_t)bb * DIM + (n0 + d)) * SEQ + s] = Ct[sl][d];
            }
        }
    }
}

__global__ __launch_bounds__(512) void flash_attn(
    const u16* __restrict__ Q, const u16* __restrict__ Kmat,
    const u16* __restrict__ VT, float* __restrict__ O)
{
    int b = blockIdx.y;
    int qt = (int)(gridDim.x - 1) - (int)blockIdx.x;
    int q0 = qt * 32;
    int tid = threadIdx.x;
    int lane = tid & 63, w = tid >> 6;
    int lo = lane & 15, qd = lane >> 4;

    __shared__ __align__(16) float Sp[8][32][33];
    __shared__ __align__(16) __bf16 Pl[32][40];
    __shared__ float ml[32], ll[32], al[32];

    const u16* Qb = Q + (size_t)b * SEQ * DIM;
    const u16* Kb = Kmat + (size_t)b * SEQ * DIM;
    const u16* VTb = VT + (size_t)b * DIM * SEQ;

    bfx8 qf[2][4];
    #pragma unroll
    for (int i = 0; i < 2; i++)
        #pragma unroll
        for (int c = 0; c < 4; c++)
            qf[i][c] = *(const bfx8*)(Qb + (size_t)(q0 + i * 16 + lo) * DIM + w * 128 + c * 32 + qd * 8);

    fx4 oacc[2][8] = {};
    if (tid < 32) { ml[tid] = -INFINITY; ll[tid] = 0.0f; }
    __syncthreads();

    for (int kt = 0; kt <= qt; kt++) {
        int k0 = kt * 32;
        fx4 sp[2][2] = {};
        #pragma unroll
        for (int c = 0; c < 4; c++) {
            bfx8 kf[2];
            #pragma unroll
            for (int jn = 0; jn < 2; jn++)
                kf[jn] = *(const bfx8*)(Kb + (size_t)(k0 + jn * 16 + lo) * DIM + w * 128 + c * 32 + qd * 8);
            #pragma unroll
            for (int i = 0; i < 2; i++)
                #pragma unroll
                for (int jn = 0; jn < 2; jn++)
                    sp[i][jn] = __builtin_amdgcn_mfma_f32_16x16x32_bf16(qf[i][c], kf[jn], sp[i][jn], 0, 0, 0);
        }
        #pragma unroll
        for (int i = 0; i < 2; i++)
            #pragma unroll
            for (int jn = 0; jn < 2; jn++)
                #pragma unroll
                for (int r = 0; r < 4; r++)
                    Sp[w][i * 16 + qd * 4 + r][jn * 16 + lo] = sp[i][jn][r];
        __syncthreads();
        {
            int r = tid >> 4, ci = tid & 15;
            int q = q0 + r;
            float s0 = 0.0f, s1 = 0.0f;
            #pragma unroll
            for (int p = 0; p < 8; p++) { s0 += Sp[p][r][ci]; s1 += Sp[p][r][ci + 16]; }
            s0 = fminf(fmaxf(s0 * SCALE, -1e30f), 1e30f);
            s1 = fminf(fmaxf(s1 * SCALE, -1e30f), 1e30f);
            if (k0 + ci > q)      s0 = -INFINITY;
            if (k0 + ci + 16 > q) s1 = -INFINITY;
            float mx = fmaxf(s0, s1);
            #pragma unroll
            for (int off = 1; off < 16; off <<= 1) mx = fmaxf(mx, __shfl_xor(mx, off));
            float mo = ml[r];
            float mn = fmaxf(mo, mx);
            float p0 = __expf(s0 - mn), p1 = __expf(s1 - mn);
            Pl[r][ci] = (__bf16)p0;
            Pl[r][ci + 16] = (__bf16)p1;
            float ps = p0 + p1;
            #pragma unroll
            for (int off = 1; off < 16; off <<= 1) ps += __shfl_xor(ps, off);
            if (ci == 0) {
                float alpha = __expf(mo - mn);
                ll[r] = alpha * ll[r] + ps;
                ml[r] = mn;
                al[r] = alpha;
            }
        }
        __syncthreads();
        float alocal[2][4];
        #pragma unroll
        for (int i = 0; i < 2; i++)
            #pragma unroll
            for (int r = 0; r < 4; r++)
                alocal[i][r] = al[i * 16 + qd * 4 + r];
        #pragma unroll
        for (int i = 0; i < 2; i++)
            #pragma unroll
            for (int j = 0; j < 8; j++)
                #pragma unroll
                for (int r = 0; r < 4; r++)
                    oacc[i][j][r] *= alocal[i][r];
        bfx8 pf[2];
        #pragma unroll
        for (int i = 0; i < 2; i++)
            pf[i] = *(const bfx8*)(&Pl[i * 16 + lo][qd * 8]);
        #pragma unroll
        for (int j = 0; j < 8; j++) {
            bfx8 vf = *(const bfx8*)(VTb + (size_t)(w * 128 + j * 16 + lo) * SEQ + k0 + qd * 8);
            #pragma unroll
            for (int i = 0; i < 2; i++)
                oacc[i][j] = __builtin_amdgcn_mfma_f32_16x16x32_bf16(pf[i], vf, oacc[i][j], 0, 0, 0);
        }
    }

    float linv[2][4];
    #pragma unroll
    for (int i = 0; i < 2; i++)
        #pragma unroll
        for (int r = 0; r < 4; r++)
            linv[i][r] = 1.0f / ll[i * 16 + qd * 4 + r];
    float* Ob = O + (size_t)b * SEQ * DIM;
    #pragma unroll
    for (int i = 0; i < 2; i++)
        #pragma unroll
        for (int j = 0; j < 8; j++)
            #pragma unroll
            for (int r = 0; r < 4; r++) {
                int row = q0 + i * 16 + qd * 4 + r;
                int col = w * 128 + j * 16 + lo;
                Ob[(size_t)row * DIM + col] = oacc[i][j][r] * linv[i][r];
            }
}

// ---------------------------------------------------------------------------
extern "C" void kernel_launch(void* const* d_in, const int* in_sizes, int n_in,
                              void* d_out, int out_size, void* d_ws, size_t ws_size,
                              hipStream_t stream) {
    const float* x  = (const float*)d_in[0];
    const float* Wq = (const float*)d_in[1];
    const float* Wk = (const float*)d_in[2];
    const float* Wv = (const float*)d_in[3];

    u16* ws = (u16*)d_ws;
    // mat-path layout: Y, VT, XB, WB(q,k straight), WTv, MT, P, Lrow
    u16* Yp  = ws;                                   // NEL (16 MiB)
    u16* VTp = ws + NEL;                             // NEL
    u16* XBp = ws + 2 * NEL;                         // NEL
    u16* WBp = ws + 3 * NEL;                         // 2 MiElem (4 MiB)
    u16* WTv = WBp + (size_t)2 * 1024 * 1024;        // 1 MiElem (2 MiB)
    u16* MTp = WTv + (size_t)1024 * 1024;            // 1 MiElem (2 MiB)
    u16* Pm  = MTp + (size_t)1024 * 1024;            // 4*SEQ*SEQ (33.6 MiB)
    float* Lrow = (float*)(Pm + (size_t)NBATCH * SEQ * SEQ);

    size_t need_mat = ((size_t)3 * NEL + (size_t)4 * 1024 * 1024
                     + (size_t)NBATCH * SEQ * SEQ) * 2
                     + (size_t)NBATCH * SEQ * 4 + 1024;   // ~92.3 MiB

    if (ws_size >= need_mat) {
        prep<<<dim3(11296), 256, 0, stream>>>(x, Wq, Wk, Wv, XBp, WBp, WTv, Lrow);
        gemm_m<<<dim3(8, 8), 256, 0, stream>>>(
            WBp + (size_t)1024 * 1024 /*WBk*/, WBp /*WBq*/, MTp);
        gemm256<<<dim3(256), 512, 0, stream>>>(XBp, MTp, WTv, Yp, VTp);
        sgemm_exp<<<dim3(544), 512, 0, stream>>>(Yp, XBp, Pm, Lrow);
        pvgemm<<<dim3(512), 512, 0, stream>>>(Pm, VTp, Lrow, (float*)d_out);
    } else {
        u16* Qp = ws; u16* Kp = ws + NEL; u16* VTf = ws + 2 * NEL;
        gemm_legacy<<<dim3(8, 64, 3), 256, 0, stream>>>(x, Wq, Wk, Wv, Qp, Kp, VTf);
        flash_attn<<<dim3(SEQ / 32, NBATCH), 512, 0, stream>>>(
            Qp, Kp, VTf, (float*)d_out);
    }
}